// Round 1
// baseline (184.361 us; speedup 1.0000x reference)
//
#include <hip/hip_runtime.h>
#include <hip/hip_bf16.h>

// RankLoss: B=8, K=16, A=120000, C=2, G=32, N=B*K=128
// Inputs (dict order):
//  0 patch_score (128,2) f32 | 1 classifications (8,120000,2) f32 | 2 bbox_id (8,16) i32
//  3 batch_num scalar i32 (unused) | 4 regressions (8,120000,4) f32 | 5 anchors (1,120000,4) f32
//  6 annotations (8,32,5) f32 | 7 label (128,1) i32 | 8 patch_img (128,4) f32
// Output: [rank_loss, reg_mean] f32

#define A_N 120000
#define B_N 8
#define K_N 16
#define N_N 128
#define G_N 32

// -------- kernel 1: masked sup_xx sweep over (n, a) pairs --------
__global__ __launch_bounds__(256) void rank_sweep(
    const float* __restrict__ patch_score,
    const float* __restrict__ cls,
    const int* __restrict__ bbox_id,
    const float* __restrict__ anchors,
    const int* __restrict__ label,
    const float* __restrict__ patch_img,
    float* __restrict__ ws_sum,
    unsigned int* __restrict__ ws_cnt)
{
    __shared__ float4 s_box[N_N];    // patch boxes
    __shared__ float  s_ab[N_N];     // area_b
    __shared__ float4 s_meta[N_N];   // ps0, ps1, (unused), idx|flag  — hit path only
    int t = threadIdx.x;
    if (t < N_N) {
        float4 b = ((const float4*)patch_img)[t];
        s_box[t] = b;
        s_ab[t]  = (b.z - b.x) * (b.w - b.y);
        int idx = bbox_id[t];
        int lz  = (label[t] == 0) ? 1 : 0;
        float4 m;
        m.x = patch_score[2 * t];
        m.y = patch_score[2 * t + 1];
        m.z = 0.0f;
        m.w = __int_as_float(idx | (lz << 30));   // idx < 2^17, flag at bit 30
        s_meta[t] = m;
    }
    __syncthreads();

    int a = blockIdx.x * blockDim.x + t;
    float lsum = 0.0f;
    unsigned int lcnt = 0;
    if (a < A_N) {
        float4 ab = ((const float4*)anchors)[a];
        float area_a = (ab.z - ab.x) * (ab.w - ab.y);
        #pragma unroll 4
        for (int n = 0; n < N_N; ++n) {
            float4 bb = s_box[n];
            float iw = fminf(ab.z, bb.z) - fmaxf(ab.x, bb.x);
            float ih = fminf(ab.w, bb.w) - fmaxf(ab.y, bb.y);
            iw = fmaxf(iw, 0.0f);
            ih = fmaxf(ih, 0.0f);
            float inter = iw * ih;
            float ua = fmaxf(area_a + s_ab[n] - inter, 1e-8f);
            // iou >= 0.6  <=>  inter >= 0.6*ua  (ua > 0)
            if (inter >= 0.6f * ua) {
                float4 mm = s_meta[n];
                int bits = __float_as_int(mm.w);
                int idx  = bits & 0x0fffffff;
                if (a != idx) {
                    lcnt++;
                    int j = n >> 4;   // K = 16
                    const float* cp = cls + ((size_t)j * A_N + a) * 2;
                    float c0 = fminf(fmaxf(cp[0], 1e-5f), 1.0f - 1e-5f);
                    float c1 = fminf(fmaxf(cp[1], 1e-5f), 1.0f - 1e-5f);
                    float contrib;
                    if (bits & (1 << 30)) {   // label == 0
                        contrib = fmaxf(mm.y - (1.0f - c0) + 0.05f, 0.0f) - logf(1.0f - c0)
                                + fmaxf(mm.y - (1.0f - c1) + 0.05f, 0.0f) - logf(1.0f - c1);
                    } else {
                        contrib = fmaxf(mm.x - c0 + 0.05f, 0.0f)
                                + fmaxf(mm.x - c1 + 0.05f, 0.0f);
                    }
                    lsum += contrib;
                }
            }
        }
    }
    // block reduction: wave shuffle then LDS
    for (int off = 32; off > 0; off >>= 1) {
        lsum += __shfl_down(lsum, off, 64);
        lcnt += __shfl_down(lcnt, off, 64);
    }
    __shared__ float s_ps[4];
    __shared__ unsigned int s_pc[4];
    int wave = t >> 6;
    if ((t & 63) == 0) { s_ps[wave] = lsum; s_pc[wave] = lcnt; }
    __syncthreads();
    if (t == 0) {
        float s = s_ps[0] + s_ps[1] + s_ps[2] + s_ps[3];
        unsigned int c = s_pc[0] + s_pc[1] + s_pc[2] + s_pc[3];
        atomicAdd(ws_sum, s);
        atomicAdd(ws_cnt, c);
    }
}

// -------- kernel 2: sup_main + regression loss + finalize --------
__global__ __launch_bounds__(256) void finalize(
    const float* __restrict__ patch_score,
    const float* __restrict__ cls,
    const int* __restrict__ bbox_id,
    const float* __restrict__ regressions,
    const float* __restrict__ anchors,
    const float* __restrict__ annotations,
    const int* __restrict__ label,
    const float* __restrict__ ws_sum,
    const unsigned int* __restrict__ ws_cnt,
    float* __restrict__ out)
{
    __shared__ float s_red[256];
    __shared__ float s_reg[B_N];
    int t = threadIdx.x;

    // sup_main: 128 rows x 2 classes
    float v = 0.0f;
    if (t < N_N) {
        int j = t >> 4;
        int idx = bbox_id[t];
        bool zero = (label[t] == 0);
        float ps0 = patch_score[2 * t];
        float ps1 = patch_score[2 * t + 1];
        const float* cp = cls + ((size_t)j * A_N + idx) * 2;
        #pragma unroll
        for (int c = 0; c < 2; ++c) {
            float cv = fminf(fmaxf(cp[c], 1e-5f), 1.0f - 1e-5f);
            if (zero)
                v += fmaxf(ps1 - (1.0f - cv) + 0.05f, 0.0f) - 0.5f * logf(1.0f - cv);
            else
                v += fmaxf(ps0 - cv + 0.05f, 0.0f);
        }
    }
    s_red[t] = v;
    __syncthreads();
    for (int off = 128; off > 0; off >>= 1) {
        if (t < off) s_red[t] += s_red[t + off];
        __syncthreads();
    }

    // regression loss: one thread per batch; only positive anchors matter
    if (t < B_N) {
        int j = t;
        int ids[K_N];
        int pos[K_N];
        int cnt = 0;
        for (int k = 0; k < K_N; ++k) {
            int a = bbox_id[j * K_N + k];
            int p = (label[j * K_N + k] == 1) ? 1 : 0;
            int f = -1;
            for (int m = 0; m < cnt; ++m) if (ids[m] == a) { f = m; break; }
            if (f >= 0) pos[f] |= p;
            else { ids[cnt] = a; pos[cnt] = p; cnt++; }
        }
        int npos = 0;
        float total = 0.0f;
        for (int m = 0; m < cnt; ++m) {
            if (!pos[m]) continue;
            npos++;
            int a = ids[m];
            float ax1 = anchors[4 * a + 0], ay1 = anchors[4 * a + 1];
            float ax2 = anchors[4 * a + 2], ay2 = anchors[4 * a + 3];
            float aw = ax2 - ax1, ah = ay2 - ay1;
            float acx = ax1 + 0.5f * aw, acy = ay1 + 0.5f * ah;
            float area_a = aw * ah;
            // argmax IoU over 32 annotations (first-max tie-break)
            float best = -1.0f; int bi = 0;
            for (int g = 0; g < G_N; ++g) {
                const float* an = annotations + ((size_t)j * G_N + g) * 5;
                float bx1 = an[0], by1 = an[1], bx2 = an[2], by2 = an[3];
                float area_b = (bx2 - bx1) * (by2 - by1);
                float iw = fmaxf(fminf(ax2, bx2) - fmaxf(ax1, bx1), 0.0f);
                float ih = fmaxf(fminf(ay2, by2) - fmaxf(ay1, by1), 0.0f);
                float inter = iw * ih;
                float ua = fmaxf(area_a + area_b - inter, 1e-8f);
                float iou = inter / ua;
                if (iou > best) { best = iou; bi = g; }
            }
            const float* as_ = annotations + ((size_t)j * G_N + bi) * 5;
            float gw = as_[2] - as_[0], gh = as_[3] - as_[1];
            float gcx = as_[0] + 0.5f * gw, gcy = as_[1] + 0.5f * gh;
            gw = fmaxf(gw, 1.0f);
            gh = fmaxf(gh, 1.0f);
            float tt[4];
            tt[0] = ((gcx - acx) / aw) / 0.1f;
            tt[1] = ((gcy - acy) / ah) / 0.1f;
            tt[2] = logf(gw / aw) / 0.2f;
            tt[3] = logf(gh / ah) / 0.2f;
            const float* rg = regressions + ((size_t)j * A_N + a) * 4;
            #pragma unroll
            for (int i = 0; i < 4; ++i) {
                float d = fabsf(tt[i] - rg[i]);
                total += (d <= 1.0f / 9.0f) ? 4.5f * d * d : d - 0.5f / 9.0f;
            }
        }
        s_reg[j] = (npos > 0) ? total / ((float)npos * 4.0f) : 0.0f;
    }
    __syncthreads();

    if (t == 0) {
        float main_sum = s_red[0];
        float rank = (main_sum + ws_sum[0]) / (float)(N_N + ws_cnt[0]);
        out[0] = rank;
        float rs = 0.0f;
        for (int j = 0; j < B_N; ++j) rs += s_reg[j];
        out[1] = rs / (float)B_N;
    }
}

extern "C" void kernel_launch(void* const* d_in, const int* in_sizes, int n_in,
                              void* d_out, int out_size, void* d_ws, size_t ws_size,
                              hipStream_t stream) {
    const float* patch_score    = (const float*)d_in[0];
    const float* classifications= (const float*)d_in[1];
    const int*   bbox_id        = (const int*)d_in[2];
    // d_in[3] batch_num unused (shapes fixed by setup_inputs)
    const float* regressions    = (const float*)d_in[4];
    const float* anchors        = (const float*)d_in[5];
    const float* annotations    = (const float*)d_in[6];
    const int*   label          = (const int*)d_in[7];
    const float* patch_img      = (const float*)d_in[8];
    float* out = (float*)d_out;

    float* ws_sum = (float*)d_ws;
    unsigned int* ws_cnt = (unsigned int*)((char*)d_ws + sizeof(float));

    // ws is poisoned 0xAA before every launch — zero the accumulators
    hipMemsetAsync(d_ws, 0, 2 * sizeof(float), stream);

    int blocks = (A_N + 255) / 256;
    rank_sweep<<<blocks, 256, 0, stream>>>(patch_score, classifications, bbox_id,
                                           anchors, label, patch_img, ws_sum, ws_cnt);
    finalize<<<1, 256, 0, stream>>>(patch_score, classifications, bbox_id,
                                    regressions, anchors, annotations, label,
                                    ws_sum, ws_cnt, out);
}

// Round 2
// 119.450 us; speedup vs baseline: 1.5434x; 1.5434x over previous
//
#include <hip/hip_runtime.h>
#include <hip/hip_bf16.h>

// RankLoss: B=8, K=16, A=120000, C=2, G=32, N=B*K=128
// Inputs (dict order):
//  0 patch_score (128,2) f32 | 1 classifications (8,120000,2) f32 | 2 bbox_id (8,16) i32
//  3 batch_num scalar i32 (unused) | 4 regressions (8,120000,4) f32 | 5 anchors (1,120000,4) f32
//  6 annotations (8,32,5) f32 | 7 label (128,1) i32 | 8 patch_img (128,4) f32
// Output: [rank_loss, reg_mean] f32

#define A_N 120000
#define B_N 8
#define K_N 16
#define N_N 128
#define G_N 32

// -------- kernel 1: masked sup_xx sweep over (n, a) pairs --------
__global__ __launch_bounds__(256) void rank_sweep(
    const float* __restrict__ patch_score,
    const float* __restrict__ cls,
    const int* __restrict__ bbox_id,
    const float* __restrict__ anchors,
    const int* __restrict__ label,
    const float* __restrict__ patch_img,
    float* __restrict__ ws_sum,
    unsigned int* __restrict__ ws_cnt)
{
    __shared__ float4 s_box[N_N];    // patch boxes
    __shared__ float  s_ab[N_N];     // area_b
    __shared__ float4 s_meta[N_N];   // ps0, ps1, (unused), idx|flag  — hit path only
    int t = threadIdx.x;
    if (t < N_N) {
        float4 b = ((const float4*)patch_img)[t];
        s_box[t] = b;
        s_ab[t]  = (b.z - b.x) * (b.w - b.y);
        int idx = bbox_id[t];
        int lz  = (label[t] == 0) ? 1 : 0;
        float4 m;
        m.x = patch_score[2 * t];
        m.y = patch_score[2 * t + 1];
        m.z = 0.0f;
        m.w = __int_as_float(idx | (lz << 30));   // idx < 2^17, flag at bit 30
        s_meta[t] = m;
    }
    __syncthreads();

    int a = blockIdx.x * blockDim.x + t;
    float lsum = 0.0f;
    unsigned int lcnt = 0;
    if (a < A_N) {
        float4 ab = ((const float4*)anchors)[a];
        float area_a = (ab.z - ab.x) * (ab.w - ab.y);
        #pragma unroll 4
        for (int n = 0; n < N_N; ++n) {
            float4 bb = s_box[n];
            float iw = fminf(ab.z, bb.z) - fmaxf(ab.x, bb.x);
            float ih = fminf(ab.w, bb.w) - fmaxf(ab.y, bb.y);
            iw = fmaxf(iw, 0.0f);
            ih = fmaxf(ih, 0.0f);
            float inter = iw * ih;
            float ua = fmaxf(area_a + s_ab[n] - inter, 1e-8f);
            // iou >= 0.6  <=>  inter >= 0.6*ua  (ua > 0)
            if (inter >= 0.6f * ua) {
                float4 mm = s_meta[n];
                int bits = __float_as_int(mm.w);
                int idx  = bits & 0x0fffffff;
                if (a != idx) {
                    lcnt++;
                    int j = n >> 4;   // K = 16
                    const float* cp = cls + ((size_t)j * A_N + a) * 2;
                    float c0 = fminf(fmaxf(cp[0], 1e-5f), 1.0f - 1e-5f);
                    float c1 = fminf(fmaxf(cp[1], 1e-5f), 1.0f - 1e-5f);
                    float contrib;
                    if (bits & (1 << 30)) {   // label == 0
                        contrib = fmaxf(mm.y - (1.0f - c0) + 0.05f, 0.0f) - logf(1.0f - c0)
                                + fmaxf(mm.y - (1.0f - c1) + 0.05f, 0.0f) - logf(1.0f - c1);
                    } else {
                        contrib = fmaxf(mm.x - c0 + 0.05f, 0.0f)
                                + fmaxf(mm.x - c1 + 0.05f, 0.0f);
                    }
                    lsum += contrib;
                }
            }
        }
    }
    // block reduction: wave shuffle then LDS
    for (int off = 32; off > 0; off >>= 1) {
        lsum += __shfl_down(lsum, off, 64);
        lcnt += __shfl_down(lcnt, off, 64);
    }
    __shared__ float s_ps[4];
    __shared__ unsigned int s_pc[4];
    int wave = t >> 6;
    if ((t & 63) == 0) { s_ps[wave] = lsum; s_pc[wave] = lcnt; }
    __syncthreads();
    if (t == 0) {
        float s = s_ps[0] + s_ps[1] + s_ps[2] + s_ps[3];
        unsigned int c = s_pc[0] + s_pc[1] + s_pc[2] + s_pc[3];
        atomicAdd(ws_sum, s);
        atomicAdd(ws_cnt, c);
    }
}

// -------- kernel 2: sup_main + regression loss + finalize (parallelized) --------
__global__ __launch_bounds__(256) void finalize(
    const float* __restrict__ patch_score,
    const float* __restrict__ cls,
    const int* __restrict__ bbox_id,
    const float* __restrict__ regressions,
    const float* __restrict__ anchors,
    const float* __restrict__ annotations,
    const int* __restrict__ label,
    const float* __restrict__ ws_sum,
    const unsigned int* __restrict__ ws_cnt,
    float* __restrict__ out)
{
    __shared__ float s_ann[B_N * G_N * 5];   // 1280 floats = 5 KB
    __shared__ int   s_id[N_N];
    __shared__ int   s_lab[N_N];
    __shared__ float s_red[256];
    __shared__ float s_tot[B_N];
    __shared__ int   s_np[B_N];
    int t = threadIdx.x;

    // ---- coalesced LDS staging ----
    for (int i = t; i < B_N * G_N * 5; i += 256) s_ann[i] = annotations[i];
    if (t < N_N) { s_id[t] = bbox_id[t]; s_lab[t] = label[t]; }
    if (t < B_N) { s_tot[t] = 0.0f; s_np[t] = 0; }
    __syncthreads();

    // ---- sup_main: 128 rows x 2 classes (parallel scattered loads) ----
    float v = 0.0f;
    int j = t >> 4;
    int k = t & 15;
    if (t < N_N) {
        int idx = s_id[t];
        bool zero = (s_lab[t] == 0);
        float ps0 = patch_score[2 * t];
        float ps1 = patch_score[2 * t + 1];
        const float* cp = cls + ((size_t)j * A_N + idx) * 2;
        float c0 = fminf(fmaxf(cp[0], 1e-5f), 1.0f - 1e-5f);
        float c1 = fminf(fmaxf(cp[1], 1e-5f), 1.0f - 1e-5f);
        if (zero) {
            v  = fmaxf(ps1 - (1.0f - c0) + 0.05f, 0.0f) - 0.5f * logf(1.0f - c0);
            v += fmaxf(ps1 - (1.0f - c1) + 0.05f, 0.0f) - 0.5f * logf(1.0f - c1);
        } else {
            v  = fmaxf(ps0 - c0 + 0.05f, 0.0f);
            v += fmaxf(ps0 - c1 + 0.05f, 0.0f);
        }
    }
    s_red[t] = v;

    // ---- regression loss: one thread per (j,k); dedup via first-occurrence ----
    float term = 0.0f;
    int isrep = 0;
    if (t < N_N) {
        int a = s_id[t];
        bool rep = true;
        int posa = 0;
        #pragma unroll
        for (int kk = 0; kk < K_N; ++kk) {
            int aa = s_id[j * K_N + kk];
            if (aa == a) {
                if (kk < k) rep = false;                 // earlier occurrence exists
                if (s_lab[j * K_N + kk] == 1) posa = 1;  // scatter-max positivity
            }
        }
        if (rep && posa) {
            isrep = 1;
            float4 ab = ((const float4*)anchors)[a];
            float aw = ab.z - ab.x, ah = ab.w - ab.y;
            float acx = ab.x + 0.5f * aw, acy = ab.y + 0.5f * ah;
            float area_a = aw * ah;
            // argmax IoU over 32 annotations from LDS (first-max tie-break)
            float best = -1.0f; int bi = 0;
            const float* annj = s_ann + j * G_N * 5;
            #pragma unroll 8
            for (int g = 0; g < G_N; ++g) {
                float bx1 = annj[5 * g + 0], by1 = annj[5 * g + 1];
                float bx2 = annj[5 * g + 2], by2 = annj[5 * g + 3];
                float area_b = (bx2 - bx1) * (by2 - by1);
                float iw = fmaxf(fminf(ab.z, bx2) - fmaxf(ab.x, bx1), 0.0f);
                float ih = fmaxf(fminf(ab.w, by2) - fmaxf(ab.y, by1), 0.0f);
                float inter = iw * ih;
                float ua = fmaxf(area_a + area_b - inter, 1e-8f);
                float iou = inter / ua;
                if (iou > best) { best = iou; bi = g; }
            }
            const float* as_ = annj + 5 * bi;
            float gw = as_[2] - as_[0], gh = as_[3] - as_[1];
            float gcx = as_[0] + 0.5f * gw, gcy = as_[1] + 0.5f * gh;
            gw = fmaxf(gw, 1.0f);
            gh = fmaxf(gh, 1.0f);
            float tt0 = ((gcx - acx) / aw) * 10.0f;       // / 0.1
            float tt1 = ((gcy - acy) / ah) * 10.0f;
            float tt2 = logf(gw / aw) * 5.0f;             // / 0.2
            float tt3 = logf(gh / ah) * 5.0f;
            float4 rg = ((const float4*)regressions)[(size_t)j * A_N + a];
            float d0 = fabsf(tt0 - rg.x);
            float d1 = fabsf(tt1 - rg.y);
            float d2 = fabsf(tt2 - rg.z);
            float d3 = fabsf(tt3 - rg.w);
            term  = (d0 <= 1.0f / 9.0f) ? 4.5f * d0 * d0 : d0 - 0.5f / 9.0f;
            term += (d1 <= 1.0f / 9.0f) ? 4.5f * d1 * d1 : d1 - 0.5f / 9.0f;
            term += (d2 <= 1.0f / 9.0f) ? 4.5f * d2 * d2 : d2 - 0.5f / 9.0f;
            term += (d3 <= 1.0f / 9.0f) ? 4.5f * d3 * d3 : d3 - 0.5f / 9.0f;
        }
    }
    __syncthreads();
    if (isrep) {
        atomicAdd(&s_tot[j], term);
        atomicAdd(&s_np[j], 1);
    }
    __syncthreads();

    // ---- reduce sup_main ----
    for (int off = 128; off > 0; off >>= 1) {
        if (t < off) s_red[t] += s_red[t + off];
        __syncthreads();
    }

    if (t == 0) {
        float rank = (s_red[0] + ws_sum[0]) / (float)(N_N + ws_cnt[0]);
        out[0] = rank;
        float rs = 0.0f;
        for (int jj = 0; jj < B_N; ++jj)
            rs += (s_np[jj] > 0) ? s_tot[jj] / ((float)s_np[jj] * 4.0f) : 0.0f;
        out[1] = rs / (float)B_N;
    }
}

extern "C" void kernel_launch(void* const* d_in, const int* in_sizes, int n_in,
                              void* d_out, int out_size, void* d_ws, size_t ws_size,
                              hipStream_t stream) {
    const float* patch_score    = (const float*)d_in[0];
    const float* classifications= (const float*)d_in[1];
    const int*   bbox_id        = (const int*)d_in[2];
    // d_in[3] batch_num unused (shapes fixed by setup_inputs)
    const float* regressions    = (const float*)d_in[4];
    const float* anchors        = (const float*)d_in[5];
    const float* annotations    = (const float*)d_in[6];
    const int*   label          = (const int*)d_in[7];
    const float* patch_img      = (const float*)d_in[8];
    float* out = (float*)d_out;

    float* ws_sum = (float*)d_ws;
    unsigned int* ws_cnt = (unsigned int*)((char*)d_ws + sizeof(float));

    // ws is poisoned 0xAA before every launch — zero the accumulators
    hipMemsetAsync(d_ws, 0, 2 * sizeof(float), stream);

    int blocks = (A_N + 255) / 256;
    rank_sweep<<<blocks, 256, 0, stream>>>(patch_score, classifications, bbox_id,
                                           anchors, label, patch_img, ws_sum, ws_cnt);
    finalize<<<1, 256, 0, stream>>>(patch_score, classifications, bbox_id,
                                    regressions, anchors, annotations, label,
                                    ws_sum, ws_cnt, out);
}